// Round 7
// baseline (524.167 us; speedup 1.0000x reference)
//
#include <hip/hip_runtime.h>

// SuperExpertMoE — round 7: round 6 (8-phase 256x256 GEMM, T2+T3/T4+T5) with epilogue
// column fix (col must include block n-offset n0).

#define TOKS 4096
#define CD 2048
#define FD 1408
#define FDP 1536      // w1 N padded to multiple of 256
#define RROWS 8192
#define NT256 56      // max 256-row m-tiles: sum ceil(cnt_e/256) (<=40) + 16 shared

typedef unsigned short u16;
typedef float f32x4 __attribute__((ext_vector_type(4)));
typedef __bf16 bf16x8 __attribute__((ext_vector_type(8)));

__device__ __forceinline__ u16 f2bf(float f) {
  unsigned u = __float_as_uint(f);
  u += 0x7fffu + ((u >> 16) & 1u);   // RNE
  return (u16)(u >> 16);
}

// ---------------- gating: one wave per token; also writes bf16 x ----------------
__global__ __launch_bounds__(256) void gate_kernel(
    const float* __restrict__ x, const float* __restrict__ gw,
    float* __restrict__ combine, float* __restrict__ part, int* __restrict__ sel,
    u16* __restrict__ xb)
{
  const int lane = threadIdx.x & 63;
  const int wave = threadIdx.x >> 6;
  const int n = blockIdx.x * 4 + wave;
  const float* xr = x + (size_t)n * CD;
  u16* xbr = xb + (size_t)n * CD;
  float p[8] = {0,0,0,0,0,0,0,0};
#pragma unroll
  for (int it = 0; it < 8; ++it) {
    const int idx = it * 256 + lane * 4;
    const float4 xv = *(const float4*)(xr + idx);
    ushort4 xo;
    xo.x = f2bf(xv.x); xo.y = f2bf(xv.y); xo.z = f2bf(xv.z); xo.w = f2bf(xv.w);
    *(ushort4*)(xbr + idx) = xo;
#pragma unroll
    for (int e = 0; e < 8; ++e) {
      const float4 gv = *(const float4*)(gw + e * CD + idx);
      p[e] += xv.x * gv.x + xv.y * gv.y + xv.z * gv.z + xv.w * gv.w;
    }
  }
#pragma unroll
  for (int e = 0; e < 8; ++e) {
#pragma unroll
    for (int m = 32; m > 0; m >>= 1) p[e] += __shfl_xor(p[e], m, 64);
  }
  float mx = p[0];
#pragma unroll
  for (int e = 1; e < 8; ++e) mx = fmaxf(mx, p[e]);
  float s = 0.f, pr[8];
#pragma unroll
  for (int e = 0; e < 8; ++e) { pr[e] = __expf(p[e] - mx); s += pr[e]; }
  const float inv = 1.f / s;
#pragma unroll
  for (int e = 0; e < 8; ++e) pr[e] *= inv;
  const float lse = mx + __logf(s);
  int i1 = 0;
#pragma unroll
  for (int e = 1; e < 8; ++e) if (pr[e] > pr[i1]) i1 = e;
  int i2 = (i1 == 0) ? 1 : 0;
#pragma unroll
  for (int e = 0; e < 8; ++e) if (e != i1 && pr[e] > pr[i2]) i2 = e;
  const float rs = 1.f / (pr[i1] + pr[i2]);

  __shared__ float pl[4][12];
  if (lane == 0) {
    float* cr = combine + (size_t)n * 16;
#pragma unroll
    for (int e = 0; e < 8; ++e) cr[e] = 0.f;
    cr[i1] = pr[i1] * rs;
    cr[i2] = pr[i2] * rs;
    cr[8] = 1.0f;
    sel[n] = i1 | (i2 << 4);
#pragma unroll
    for (int e = 0; e < 8; ++e) pl[wave][e] = pr[e];
    pl[wave][8] = lse * lse;
  }
  __syncthreads();
  if (threadIdx.x < 9)
    part[(size_t)blockIdx.x * 16 + threadIdx.x] =
        pl[0][threadIdx.x] + pl[1][threadIdx.x] + pl[2][threadIdx.x] + pl[3][threadIdx.x];
}

// ---------------- routing compaction + flat 256-row tile map ----------------
__global__ void route_kernel(const int* __restrict__ sel, int* __restrict__ le,
                             int* __restrict__ pos, int* __restrict__ cntoff,
                             int* __restrict__ tileMap)
{
  const int lane = threadIdx.x;
  const unsigned long long lt = (1ull << lane) - 1ull;
  int cnt[8] = {0,0,0,0,0,0,0,0};
  for (int c = 0; c < TOKS / 64; ++c) {
    const int s = sel[c * 64 + lane];
    const int e1 = s & 15, e2 = (s >> 4) & 15;
#pragma unroll
    for (int e = 0; e < 8; ++e)
      cnt[e] += __popcll(__ballot(e1 == e)) + __popcll(__ballot(e2 == e));
  }
  int off[8]; off[0] = 0;
#pragma unroll
  for (int e = 1; e < 8; ++e) off[e] = off[e - 1] + cnt[e - 1];
  int base[8];
#pragma unroll
  for (int e = 0; e < 8; ++e) base[e] = off[e];
  for (int c = 0; c < TOKS / 64; ++c) {
    const int n = c * 64 + lane;
    const int s = sel[n];
    const int e1 = s & 15, e2 = (s >> 4) & 15;
#pragma unroll
    for (int e = 0; e < 8; ++e) {
      const unsigned long long m1 = __ballot(e1 == e);
      const unsigned long long m2 = __ballot(e2 == e);
      if (e1 == e) { const int r = base[e] + __popcll(m1 & lt); le[r] = n; pos[2 * n] = r; }
      if (e2 == e) { const int r = base[e] + __popcll(m1) + __popcll(m2 & lt); le[r] = n; pos[2 * n + 1] = r; }
      base[e] += __popcll(m1) + __popcll(m2);
    }
  }
  if (lane < 8) { cntoff[lane] = cnt[lane]; cntoff[16 + lane] = off[lane]; }
  if (lane == 8) { cntoff[8] = TOKS; cntoff[24] = RROWS; }
  if (lane == 0) {
    int t = 0;
    for (int e = 0; e < 8; ++e)
      for (int m = 0; m < cnt[e]; m += 256) tileMap[t++] = e | (m << 4);
    for (int m = 0; m < TOKS; m += 256) tileMap[t++] = 8 | (m << 4);
    cntoff[25] = t;   // NT <= 56
  }
}

// deterministic tree reduce -> loss scalar
__global__ void finalize_kernel(const float* __restrict__ part, float* __restrict__ loss_out)
{
  __shared__ float sm[256][10];
  float loc[9] = {0,0,0,0,0,0,0,0,0};
  for (int b = threadIdx.x; b < 1024; b += 256)
#pragma unroll
    for (int c = 0; c < 9; ++c) loc[c] += part[(size_t)b * 16 + c];
#pragma unroll
  for (int c = 0; c < 9; ++c) sm[threadIdx.x][c] = loc[c];
  __syncthreads();
  for (int off = 128; off > 0; off >>= 1) {
    if (threadIdx.x < off)
#pragma unroll
      for (int c = 0; c < 9; ++c) sm[threadIdx.x][c] += sm[threadIdx.x + off][c];
    __syncthreads();
  }
  if (threadIdx.x == 0) {
    float aux = 0.f;
#pragma unroll
    for (int e = 0; e < 8; ++e) { const float m = sm[0][e] * (1.f / TOKS); aux += m * m; }
    const float z = sm[0][8] * (1.f / TOKS);
    loss_out[0] = 0.01f * aux + 0.001f * z;
  }
}

// ---------------- cast: w1/sw1 -> w1b padded [9][1536][2048], w2/sw2 -> w2b [9][2048][1408]
#define S1E  786432    // 1536*2048/4 slots per expert
#define S2E  720896    // 2048*1408/4
__global__ void cast_all_kernel(const float* __restrict__ w1, const float* __restrict__ sw1,
                                const float* __restrict__ w2, const float* __restrict__ sw2,
                                u16* __restrict__ w1b, u16* __restrict__ w2b)
{
  const int total = 9 * (S1E + S2E);
  int i = blockIdx.x * blockDim.x + threadIdx.x;
  const int stride = gridDim.x * blockDim.x;
  for (; i < total; i += stride) {
    ushort4 o;
    u16* dst;
    if (i < 9 * S1E) {
      const int e = i / S1E, rem = i - e * S1E;
      const int r = rem >> 9, g = rem & 511;       // r<1536, g<512
      dst = w1b + ((size_t)e * FDP + r) * CD + g * 4;
      if (r < FD) {
        const float* src = (e < 8) ? (w1 + ((size_t)e * FD + r) * CD) : (sw1 + (size_t)r * CD);
        const float4 v = *(const float4*)(src + g * 4);
        o.x = f2bf(v.x); o.y = f2bf(v.y); o.z = f2bf(v.z); o.w = f2bf(v.w);
      } else {
        o.x = o.y = o.z = o.w = 0;
      }
    } else {
      const int j = i - 9 * S1E;
      const int e = j / S2E, rem = j - e * S2E;
      const int r = rem / 352, g = rem % 352;      // r<2048, g<352
      const float* src = (e < 8) ? (w2 + ((size_t)e * CD + r) * FD) : (sw2 + (size_t)r * FD);
      const float4 v = *(const float4*)(src + g * 4);
      o.x = f2bf(v.x); o.y = f2bf(v.y); o.z = f2bf(v.z); o.w = f2bf(v.w);
      dst = w2b + ((size_t)e * CD + r) * FD + g * 4;
    }
    *(ushort4*)dst = o;
  }
}

// ---------------- 8-phase GEMM: BM=BN=256, BK=64, 8 waves (2M x 4N), dbuf LDS 128KB ------
// Phase p computes block quadrant (mh,nh) in order (0,0),(0,1),(1,1),(1,0).
// Stage stream: iter t stages A1,B0 of tile t+1 (other buf) at p0,p1; A0,B1 of tile t+2
// (current buf, slots past last read) at p2,p3. One vmcnt(4) per K-tile; drains only at tail.
// LDS swizzle: physical 16B-group slot g of row r holds logical group g^(r&7) (pre-swizzled
// global source, linear LDS dest; reads apply the same XOR).

#define LDSR(base, r, gg) (*(const bf16x8*)((base) + (r) * 64 + ((((gg) ^ ((r) & 7))) << 3)))

#define PHASE(mh, nh, STG)                                                                     \
  {                                                                                            \
    asm volatile("" ::: "memory");                                                             \
    __builtin_amdgcn_s_barrier();                                                              \
    asm volatile("" ::: "memory");                                                             \
    STG;                                                                                       \
    const u16* sa_ = &smA[cur][0];                                                             \
    const u16* sb_ = &smB[cur][0];                                                             \
    _Pragma("unroll")                                                                          \
    for (int kk = 0; kk < 2; ++kk) {                                                           \
      const int gg = kk * 4 + g16;                                                             \
      const int ra = (mh) * 128 + wm * 64 + la15;                                              \
      const int rb = (nh) * 128 + wn * 32 + la15;                                              \
      const bf16x8 af0 = LDSR(sa_, ra,      gg);                                               \
      const bf16x8 af1 = LDSR(sa_, ra + 16, gg);                                               \
      const bf16x8 af2 = LDSR(sa_, ra + 32, gg);                                               \
      const bf16x8 af3 = LDSR(sa_, ra + 48, gg);                                               \
      const bf16x8 bv0 = LDSR(sb_, rb,      gg);                                               \
      const bf16x8 bv1 = LDSR(sb_, rb + 16, gg);                                               \
      __builtin_amdgcn_s_setprio(1);                                                           \
      acc[(mh)*4+0][(nh)*2+0] = __builtin_amdgcn_mfma_f32_16x16x32_bf16(af0, bv0, acc[(mh)*4+0][(nh)*2+0], 0, 0, 0); \
      acc[(mh)*4+1][(nh)*2+0] = __builtin_amdgcn_mfma_f32_16x16x32_bf16(af1, bv0, acc[(mh)*4+1][(nh)*2+0], 0, 0, 0); \
      acc[(mh)*4+2][(nh)*2+0] = __builtin_amdgcn_mfma_f32_16x16x32_bf16(af2, bv0, acc[(mh)*4+2][(nh)*2+0], 0, 0, 0); \
      acc[(mh)*4+3][(nh)*2+0] = __builtin_amdgcn_mfma_f32_16x16x32_bf16(af3, bv0, acc[(mh)*4+3][(nh)*2+0], 0, 0, 0); \
      acc[(mh)*4+0][(nh)*2+1] = __builtin_amdgcn_mfma_f32_16x16x32_bf16(af0, bv1, acc[(mh)*4+0][(nh)*2+1], 0, 0, 0); \
      acc[(mh)*4+1][(nh)*2+1] = __builtin_amdgcn_mfma_f32_16x16x32_bf16(af1, bv1, acc[(mh)*4+1][(nh)*2+1], 0, 0, 0); \
      acc[(mh)*4+2][(nh)*2+1] = __builtin_amdgcn_mfma_f32_16x16x32_bf16(af2, bv1, acc[(mh)*4+2][(nh)*2+1], 0, 0, 0); \
      acc[(mh)*4+3][(nh)*2+1] = __builtin_amdgcn_mfma_f32_16x16x32_bf16(af3, bv1, acc[(mh)*4+3][(nh)*2+1], 0, 0, 0); \
      __builtin_amdgcn_s_setprio(0);                                                           \
    }                                                                                          \
  }

template<int MODE>
__global__ __launch_bounds__(512, 2) void gemm8p(
    const u16* __restrict__ Abase, const u16* __restrict__ Bbase,
    u16* __restrict__ outBF, const float* __restrict__ combine,
    const int* __restrict__ le, const int* __restrict__ cntoff,
    const int* __restrict__ tileMap)
{
  constexpr int K   = (MODE == 0) ? CD : FD;     // 2048 / 1408
  constexpr int BS  = (MODE == 0) ? FDP : CD;    // B row count (padded for up)
  constexpr int OS  = (MODE == 0) ? FD : CD;     // out row stride
  constexpr int NY  = (MODE == 0) ? 6 : 8;
  constexpr int NKT = K >> 6;                    // 32 / 22
  constexpr int Q   = NT256 * NY / 8;            // 42 / 56 (exact)

  __shared__ __attribute__((aligned(16))) u16 smA[2][256 * 64];  // 2 x 32 KB
  __shared__ __attribute__((aligned(16))) u16 smB[2][256 * 64];  // 2 x 32 KB -> 128 KB

  const int orig = blockIdx.x + gridDim.x * blockIdx.y;
  const int wgid = (orig & 7) * Q + (orig >> 3);
  const int tix = wgid / NY;
  const int y = wgid - tix * NY;
  const int NT = cntoff[25];
  if (tix >= NT) return;
  const int packed = tileMap[tix];
  const int e = packed & 15;
  const int m0 = packed >> 4;
  const int cnt = cntoff[e];
  const int off = cntoff[16 + e];
  const int n0 = y * 256;

  const int tid  = threadIdx.x;
  const int ln   = tid & 63;
  const int wv   = tid >> 6;
  const int wm   = wv >> 2;        // 0..1
  const int wn   = wv & 3;         // 0..3
  const int la15 = ln & 15;
  const int g16  = ln >> 4;        // 0..3

  const u16* Bp = Bbase + (size_t)e * (size_t)BS * K;

  // staging: thread covers rows h*128 + (wv*2+l)*8 + (ln>>3), pre-swizzled 16B group
  const int srow = ln >> 3;                       // 0..7
  const int sgrp = (((ln & 7) ^ srow) << 3);      // pre-swizzled elem offset
  const u16* pA[2][2];
  const u16* pB[2][2];
#pragma unroll
  for (int h = 0; h < 2; ++h)
#pragma unroll
    for (int l = 0; l < 2; ++l) {
      const int rloc = h * 128 + (wv * 2 + l) * 8 + srow;
      size_t arow;
      if (MODE == 0)
        arow = (e == 8) ? (size_t)(m0 + rloc)
                        : (size_t)le[min(off + m0 + rloc, RROWS - 1)];
      else
        arow = (size_t)(off + m0 + rloc);
      pA[h][l] = Abase + arow * K + sgrp;
      pB[h][l] = Bp + (size_t)(n0 + h * 128 + (wv * 2 + l) * 8 + srow) * K + sgrp;
    }

#define SA(buf, h, kt)                                                                         \
  _Pragma("unroll")                                                                            \
  for (int l_ = 0; l_ < 2; ++l_)                                                               \
    __builtin_amdgcn_global_load_lds(                                                          \
        (const __attribute__((address_space(1))) void*)(pA[h][l_] + (kt) * 64),                \
        (__attribute__((address_space(3))) void*)(&smA[buf][(h) * 8192 + (wv * 2 + l_) * 512]),\
        16, 0, 0);
#define SB(buf, h, kt)                                                                         \
  _Pragma("unroll")                                                                            \
  for (int l_ = 0; l_ < 2; ++l_)                                                               \
    __builtin_amdgcn_global_load_lds(                                                          \
        (const __attribute__((address_space(1))) void*)(pB[h][l_] + (kt) * 64),                \
        (__attribute__((address_space(3))) void*)(&smB[buf][(h) * 8192 + (wv * 2 + l_) * 512]),\
        16, 0, 0);

  f32x4 acc[8][4] = {};

  // prologue stream: A0(0), B1(0), A1(0), B0(0), A0(1), B1(1)
  SA(0, 0, 0); SB(0, 1, 0); SA(0, 1, 0); SB(0, 0, 0); SA(1, 0, 1); SB(1, 1, 1);

#pragma unroll 1
  for (int t = 0; t < NKT; ++t) {
    const int cur = t & 1;
    if (t < NKT - 1) { asm volatile("s_waitcnt vmcnt(4)" ::: "memory"); }
    else             { asm volatile("s_waitcnt vmcnt(0)" ::: "memory"); }
    PHASE(0, 0, if (t + 1 < NKT) { SA(cur ^ 1, 1, t + 1) })
    PHASE(0, 1, if (t + 1 < NKT) { SB(cur ^ 1, 0, t + 1) })
    PHASE(1, 1, if (t + 2 < NKT) { SA(cur, 0, t + 2) })
    PHASE(1, 0, if (t + 2 < NKT) { SB(cur, 1, t + 2) })
  }

  // epilogue — C/D layout: col = lane&15, row = (lane>>4)*4 + q
#pragma unroll
  for (int mi = 0; mi < 8; ++mi) {
    const int rq = (mi >> 2) * 128 + wm * 64 + (mi & 3) * 16 + g16 * 4;
#pragma unroll
    for (int q = 0; q < 4; ++q) {
      const int rloc = rq + q;
      if (m0 + rloc >= cnt) continue;
      float sc = 1.f;
      if (MODE == 0) {
        const int tok = (e == 8) ? (m0 + rloc) : le[off + m0 + rloc];
        sc = combine[(size_t)tok * 16 + e];
      }
#pragma unroll
      for (int ni = 0; ni < 4; ++ni) {
        const int col = n0 + (ni >> 1) * 128 + wn * 32 + (ni & 1) * 16 + la15;   // FIX: + n0
        if (MODE == 0 && col >= FD) continue;
        const float v = acc[mi][ni][q];
        const float h = (MODE == 0) ? (sc * v * (1.f / (1.f + __expf(-v)))) : v;
        outBF[(size_t)(off + m0 + rloc) * OS + col] = f2bf(h);
      }
    }
  }
#undef SA
#undef SB
}

// ---------------- gather-sum: out[n] = alpha*(Yc[p1]+Yc[p2]+Yc[8192+n]) + beta*x[n] --------
__global__ __launch_bounds__(256) void gather_kernel(
    const u16* __restrict__ Yc, const int* __restrict__ pos,
    const float* __restrict__ x, const float* __restrict__ alpha,
    const float* __restrict__ beta, float* __restrict__ out)
{
  const int n = blockIdx.x;
  const int c0 = threadIdx.x * 8;
  const int p1 = pos[2 * n], p2 = pos[2 * n + 1];
  const bf16x8 a = *(const bf16x8*)(Yc + (size_t)p1 * CD + c0);
  const bf16x8 b = *(const bf16x8*)(Yc + (size_t)p2 * CD + c0);
  const bf16x8 s = *(const bf16x8*)(Yc + ((size_t)RROWS + n) * CD + c0);
  const float* xr = x + (size_t)n * CD + c0;
  float* orow = out + (size_t)n * CD + c0;
#pragma unroll
  for (int j = 0; j < 8; ++j) {
    const float v = (float)a[j] + (float)b[j] + (float)s[j];
    orow[j] = alpha[c0 + j] * v + beta[c0 + j] * xr[j];
  }
}

extern "C" void kernel_launch(void* const* d_in, const int* in_sizes, int n_in,
                              void* d_out, int out_size, void* d_ws, size_t ws_size,
                              hipStream_t stream)
{
  (void)in_sizes; (void)n_in; (void)out_size; (void)ws_size;
  const float* x     = (const float*)d_in[0];
  const float* gw    = (const float*)d_in[1];
  const float* w1    = (const float*)d_in[2];
  const float* w2    = (const float*)d_in[3];
  const float* sw1   = (const float*)d_in[4];
  const float* sw2   = (const float*)d_in[5];
  const float* alpha = (const float*)d_in[6];
  const float* beta  = (const float*)d_in[7];
  float* out = (float*)d_out;

  char* ws = (char*)d_ws;
  float* combine = (float*)(ws + 0);            // 256 KB
  float* part    = (float*)(ws + 262144);       // 64 KB
  int*   sel     = (int*)(ws + 327680);         // 16 KB
  int*   le      = (int*)(ws + 344064);         // 32 KB
  int*   pos     = (int*)(ws + 376832);         // 32 KB
  int*   cntoff  = (int*)(ws + 409600);         // 256 B
  int*   tileMap = (int*)(ws + 409856);         // 512 B
  u16*   xb      = (u16*)(ws + 410368);         // 16.8 MB
  u16*   w1b     = (u16*)(ws + 17187584);       // 9*1536*2048*2 = 56.6 MB (padded)
  u16*   w2b     = (u16*)(ws + 73810688);       // 9*2048*1408*2 = 51.9 MB
  u16*   Hcomp   = (u16*)(ws + 125715200);      // 12288*1408*2 = 34.6 MB
  u16*   Ycomp   = (u16*)(ws + 160318208);      // 12288*2048*2 = 50.3 MB  (end ~201 MB)

  gate_kernel<<<1024, 256, 0, stream>>>(x, gw, combine, part, sel, xb);
  route_kernel<<<1, 64, 0, stream>>>(sel, le, pos, cntoff, tileMap);
  finalize_kernel<<<1, 256, 0, stream>>>(part, out + (size_t)TOKS * CD);
  cast_all_kernel<<<4096, 256, 0, stream>>>(w1, sw1, w2, sw2, w1b, w2b);
  gemm8p<0><<<dim3(NT256, 6), 512, 0, stream>>>(xb, w1b, Hcomp, combine, le, cntoff, tileMap);
  gemm8p<1><<<dim3(NT256, 8), 512, 0, stream>>>(Hcomp, w2b, Ycomp, nullptr, nullptr, cntoff, tileMap);
  gather_kernel<<<TOKS, 256, 0, stream>>>(Ycomp, pos, x, alpha, beta, out);
}

// Round 8
// 410.572 us; speedup vs baseline: 1.2767x; 1.2767x over previous
//
#include <hip/hip_runtime.h>

// SuperExpertMoE — round 8: 128x128 2-phase GEMM with stage-AHEAD double-buffer
// (T3-minimal recipe: STAGE(next) -> compute(cur) -> vmcnt(0)+barrier), T2 swizzle kept.
// gate(+xb) -> route(128-tile map) -> finalize -> cast -> up GEMM -> down GEMM -> gather.

#define TOKS 4096
#define CD 2048
#define FD 1408
#define RROWS 8192    // exactly 2 routed slots per token
#define NTMAX 104     // max 128-row m-tiles: sum ceil(cnt_e/128) (<=71) + 32 shared

typedef unsigned short u16;
typedef float f32x4 __attribute__((ext_vector_type(4)));
typedef __bf16 bf16x8 __attribute__((ext_vector_type(8)));

__device__ __forceinline__ u16 f2bf(float f) {
  unsigned u = __float_as_uint(f);
  u += 0x7fffu + ((u >> 16) & 1u);   // RNE
  return (u16)(u >> 16);
}

// ---------------- gating: one wave per token; also writes bf16 x ----------------
__global__ __launch_bounds__(256) void gate_kernel(
    const float* __restrict__ x, const float* __restrict__ gw,
    float* __restrict__ combine, float* __restrict__ part, int* __restrict__ sel,
    u16* __restrict__ xb)
{
  const int lane = threadIdx.x & 63;
  const int wave = threadIdx.x >> 6;
  const int n = blockIdx.x * 4 + wave;
  const float* xr = x + (size_t)n * CD;
  u16* xbr = xb + (size_t)n * CD;
  float p[8] = {0,0,0,0,0,0,0,0};
#pragma unroll
  for (int it = 0; it < 8; ++it) {
    const int idx = it * 256 + lane * 4;
    const float4 xv = *(const float4*)(xr + idx);
    ushort4 xo;
    xo.x = f2bf(xv.x); xo.y = f2bf(xv.y); xo.z = f2bf(xv.z); xo.w = f2bf(xv.w);
    *(ushort4*)(xbr + idx) = xo;
#pragma unroll
    for (int e = 0; e < 8; ++e) {
      const float4 gv = *(const float4*)(gw + e * CD + idx);
      p[e] += xv.x * gv.x + xv.y * gv.y + xv.z * gv.z + xv.w * gv.w;
    }
  }
#pragma unroll
  for (int e = 0; e < 8; ++e) {
#pragma unroll
    for (int m = 32; m > 0; m >>= 1) p[e] += __shfl_xor(p[e], m, 64);
  }
  float mx = p[0];
#pragma unroll
  for (int e = 1; e < 8; ++e) mx = fmaxf(mx, p[e]);
  float s = 0.f, pr[8];
#pragma unroll
  for (int e = 0; e < 8; ++e) { pr[e] = __expf(p[e] - mx); s += pr[e]; }
  const float inv = 1.f / s;
#pragma unroll
  for (int e = 0; e < 8; ++e) pr[e] *= inv;
  const float lse = mx + __logf(s);
  int i1 = 0;
#pragma unroll
  for (int e = 1; e < 8; ++e) if (pr[e] > pr[i1]) i1 = e;   // strict > : lowest-index tie-break
  int i2 = (i1 == 0) ? 1 : 0;
#pragma unroll
  for (int e = 0; e < 8; ++e) if (e != i1 && pr[e] > pr[i2]) i2 = e;
  const float rs = 1.f / (pr[i1] + pr[i2]);

  __shared__ float pl[4][12];
  if (lane == 0) {
    float* cr = combine + (size_t)n * 16;
#pragma unroll
    for (int e = 0; e < 8; ++e) cr[e] = 0.f;
    cr[i1] = pr[i1] * rs;
    cr[i2] = pr[i2] * rs;
    cr[8] = 1.0f;
    sel[n] = i1 | (i2 << 4);
#pragma unroll
    for (int e = 0; e < 8; ++e) pl[wave][e] = pr[e];
    pl[wave][8] = lse * lse;
  }
  __syncthreads();
  if (threadIdx.x < 9)
    part[(size_t)blockIdx.x * 16 + threadIdx.x] =
        pl[0][threadIdx.x] + pl[1][threadIdx.x] + pl[2][threadIdx.x] + pl[3][threadIdx.x];
}

// ---------------- routing compaction (single wave, deterministic) + 128-row tile map -----
__global__ void route_kernel(const int* __restrict__ sel, int* __restrict__ le,
                             int* __restrict__ pos, int* __restrict__ cntoff,
                             int* __restrict__ tileMap)
{
  const int lane = threadIdx.x;
  const unsigned long long lt = (1ull << lane) - 1ull;
  int cnt[8] = {0,0,0,0,0,0,0,0};
  for (int c = 0; c < TOKS / 64; ++c) {
    const int s = sel[c * 64 + lane];
    const int e1 = s & 15, e2 = (s >> 4) & 15;
#pragma unroll
    for (int e = 0; e < 8; ++e)
      cnt[e] += __popcll(__ballot(e1 == e)) + __popcll(__ballot(e2 == e));
  }
  int off[8]; off[0] = 0;
#pragma unroll
  for (int e = 1; e < 8; ++e) off[e] = off[e - 1] + cnt[e - 1];
  int base[8];
#pragma unroll
  for (int e = 0; e < 8; ++e) base[e] = off[e];
  for (int c = 0; c < TOKS / 64; ++c) {
    const int n = c * 64 + lane;
    const int s = sel[n];
    const int e1 = s & 15, e2 = (s >> 4) & 15;
#pragma unroll
    for (int e = 0; e < 8; ++e) {
      const unsigned long long m1 = __ballot(e1 == e);
      const unsigned long long m2 = __ballot(e2 == e);
      if (e1 == e) { const int r = base[e] + __popcll(m1 & lt); le[r] = n; pos[2 * n] = r; }
      if (e2 == e) { const int r = base[e] + __popcll(m1) + __popcll(m2 & lt); le[r] = n; pos[2 * n + 1] = r; }
      base[e] += __popcll(m1) + __popcll(m2);
    }
  }
  if (lane < 8) { cntoff[lane] = cnt[lane]; cntoff[16 + lane] = off[lane]; }
  if (lane == 8) { cntoff[8] = TOKS; cntoff[24] = RROWS; }
  if (lane == 0) {
    int t = 0;
    for (int e = 0; e < 8; ++e)
      for (int m = 0; m < cnt[e]; m += 128) tileMap[t++] = e | (m << 4);
    for (int m = 0; m < TOKS; m += 128) tileMap[t++] = 8 | (m << 4);
    cntoff[25] = t;   // NT <= 104
  }
}

// deterministic tree reduce -> loss scalar
__global__ void finalize_kernel(const float* __restrict__ part, float* __restrict__ loss_out)
{
  __shared__ float sm[256][10];
  float loc[9] = {0,0,0,0,0,0,0,0,0};
  for (int b = threadIdx.x; b < 1024; b += 256)
#pragma unroll
    for (int c = 0; c < 9; ++c) loc[c] += part[(size_t)b * 16 + c];
#pragma unroll
  for (int c = 0; c < 9; ++c) sm[threadIdx.x][c] = loc[c];
  __syncthreads();
  for (int off = 128; off > 0; off >>= 1) {
    if (threadIdx.x < off)
#pragma unroll
      for (int c = 0; c < 9; ++c) sm[threadIdx.x][c] += sm[threadIdx.x + off][c];
    __syncthreads();
  }
  if (threadIdx.x == 0) {
    float aux = 0.f;
#pragma unroll
    for (int e = 0; e < 8; ++e) { const float m = sm[0][e] * (1.f / TOKS); aux += m * m; }
    const float z = sm[0][8] * (1.f / TOKS);
    loss_out[0] = 0.01f * aux + 0.001f * z;
  }
}

// ---------------- fused cast: w1, sw1, w2, sw2 -> bf16 ----------------
#define W14  5767168   // 8*FD*CD/4
#define SW14 720896    // FD*CD/4
__global__ void cast_all_kernel(const float4* __restrict__ w1, const float4* __restrict__ sw1,
                                const float4* __restrict__ w2, const float4* __restrict__ sw2,
                                u16* __restrict__ w1b, u16* __restrict__ w2b)
{
  const int total = 2 * (W14 + SW14);
  int i = blockIdx.x * blockDim.x + threadIdx.x;
  const int stride = gridDim.x * blockDim.x;
  for (; i < total; i += stride) {
    int j = i;
    const float4* src; u16* dst;
    if (j < W14)                   { src = w1;  dst = w1b; }
    else if ((j -= W14) < SW14)    { src = sw1; dst = w1b + (size_t)8 * FD * CD; }
    else if ((j -= SW14) < W14)    { src = w2;  dst = w2b; }
    else                           { j -= W14; src = sw2; dst = w2b + (size_t)8 * CD * FD; }
    const float4 v = src[j];
    ushort4 o;
    o.x = f2bf(v.x); o.y = f2bf(v.y); o.z = f2bf(v.z); o.w = f2bf(v.w);
    *(ushort4*)(dst + (size_t)j * 4) = o;
  }
}

// ---------------- GEMM: 128x128, BK=64, 4 waves, dbuf LDS, stage-ahead 2-phase ----------
// MODE 0 (up):   A = xb gathered via le; B = w1b[e]; out Hcomp (silu*combine), K=CD, NY=11.
// MODE 1 (down): A = Hcomp (compacted rows); B = w2b[e]; out Ycomp, K=FD, NY=16.
// LDS tile [128][64] bf16; physical 16B-group slot s of row r holds logical group s^(r&7)
// (pre-swizzled global source + linear gload_lds dest; reads apply the same XOR).
template<int MODE>
__global__ __launch_bounds__(256, 2) void gemm_bt(
    const u16* __restrict__ Abase, const u16* __restrict__ Bbase,
    u16* __restrict__ outBF, const float* __restrict__ combine,
    const int* __restrict__ le, const int* __restrict__ cntoff,
    const int* __restrict__ tileMap)
{
  constexpr int K   = (MODE == 0) ? CD : FD;
  constexpr int OS  = (MODE == 0) ? FD : CD;
  constexpr int NY  = (MODE == 0) ? 11 : 16;
  constexpr int NKT = K >> 6;                 // 32 / 22
  constexpr int Q   = NTMAX * NY / 8;         // 143 / 208 (exact)

  __shared__ __attribute__((aligned(16))) u16 smA[2][128 * 64];  // 2 x 16 KB
  __shared__ __attribute__((aligned(16))) u16 smB[2][128 * 64];  // 2 x 16 KB -> 64 KB

  // bijective XCD-chunk swizzle: contiguous logical ids (same expert) -> same XCD
  const int orig = blockIdx.x + gridDim.x * blockIdx.y;
  const int wgid = (orig & 7) * Q + (orig >> 3);
  const int t = wgid / NY;
  const int y = wgid - t * NY;
  const int NT = cntoff[25];
  if (t >= NT) return;
  const int packed = tileMap[t];
  const int e = packed & 15;
  const int m0 = packed >> 4;
  const int cnt = cntoff[e];
  const int off = cntoff[16 + e];
  const int n0 = y * 128;

  const int tid  = threadIdx.x;
  const int ln   = tid & 63;
  const int wv   = tid >> 6;
  const int wr   = wv >> 1, wc = wv & 1;
  const int la15 = ln & 15;
  const int g16  = ln >> 4;      // 0..3

  const u16* Bp = Bbase + (size_t)e * FD * CD;

  // staging geometry: iteration c covers rows c*32 + wv*8 + (ln>>3), pre-swizzled 16B group
  const int srow = ln >> 3;                        // 0..7
  const int sgrp = (((ln & 7) ^ srow) << 3);       // element offset 0..56 (pre-swizzled)
  const u16* pA[4];
  const u16* pB[4];
#pragma unroll
  for (int c = 0; c < 4; ++c) {
    const int rloc = c * 32 + wv * 8 + srow;
    size_t arow;
    if (MODE == 0)
      arow = (e == 8) ? (size_t)(m0 + rloc)
                      : (size_t)le[min(off + m0 + rloc, RROWS - 1)];
    else
      arow = (size_t)(off + m0 + rloc);
    pA[c] = Abase + arow * K + sgrp;
    pB[c] = Bp + (size_t)(n0 + rloc) * K + sgrp;
  }

#define STAGE(buf, kt)                                                                        \
  {                                                                                           \
    const int kof_ = (kt) << 6;                                                               \
    _Pragma("unroll")                                                                         \
    for (int c_ = 0; c_ < 4; ++c_) {                                                          \
      __builtin_amdgcn_global_load_lds(                                                       \
          (const __attribute__((address_space(1))) void*)(pA[c_] + kof_),                     \
          (__attribute__((address_space(3))) void*)(&smA[buf][c_ * 2048 + wv * 512]),         \
          16, 0, 0);                                                                          \
      __builtin_amdgcn_global_load_lds(                                                       \
          (const __attribute__((address_space(1))) void*)(pB[c_] + kof_),                     \
          (__attribute__((address_space(3))) void*)(&smB[buf][c_ * 2048 + wv * 512]),         \
          16, 0, 0);                                                                          \
    }                                                                                         \
  }

  f32x4 acc[4][4] = {};

  // prologue: tile 0 staged, wait, barrier
  STAGE(0, 0)
  asm volatile("s_waitcnt vmcnt(0)" ::: "memory");
  __builtin_amdgcn_s_barrier();
  asm volatile("" ::: "memory");

#pragma unroll 1
  for (int kt = 0; kt < NKT; ++kt) {
    const int cur = kt & 1;
    if (kt + 1 < NKT) STAGE(cur ^ 1, kt + 1)       // issue next tile BEFORE compute
    // compute current tile
    const u16* sa = &smA[cur][0];
    const u16* sb = &smB[cur][0];
#pragma unroll
    for (int kk = 0; kk < 2; ++kk) {
      const int gg = kk * 4 + g16;
      bf16x8 af[4], bv[4];
#pragma unroll
      for (int i = 0; i < 4; ++i) {
        const int r = wr * 64 + i * 16 + la15;
        af[i] = *(const bf16x8*)(sa + r * 64 + (((gg ^ (r & 7))) << 3));
      }
#pragma unroll
      for (int j = 0; j < 4; ++j) {
        const int r = wc * 64 + j * 16 + la15;
        bv[j] = *(const bf16x8*)(sb + r * 64 + (((gg ^ (r & 7))) << 3));
      }
#pragma unroll
      for (int i = 0; i < 4; ++i)
#pragma unroll
        for (int j = 0; j < 4; ++j)
          acc[i][j] = __builtin_amdgcn_mfma_f32_16x16x32_bf16(af[i], bv[j], acc[i][j], 0, 0, 0);
    }
    if (kt + 1 < NKT) {
      asm volatile("s_waitcnt vmcnt(0)" ::: "memory");   // next tile landed
      asm volatile("" ::: "memory");
      __builtin_amdgcn_s_barrier();                       // all waves done reading cur
      asm volatile("" ::: "memory");
    }
  }
#undef STAGE

  // epilogue — C/D layout: col = lane&15, row = (lane>>4)*4 + q
#pragma unroll
  for (int i = 0; i < 4; ++i) {
    const int rloc0 = wr * 64 + i * 16 + (g16 << 2);
#pragma unroll
    for (int q = 0; q < 4; ++q) {
      const int rloc = rloc0 + q;
      if (m0 + rloc >= cnt) continue;
      float sc = 1.f;
      if (MODE == 0) {
        const int tok = (e == 8) ? (m0 + rloc) : le[off + m0 + rloc];
        sc = combine[(size_t)tok * 16 + e];
      }
#pragma unroll
      for (int j = 0; j < 4; ++j) {
        const int col = n0 + wc * 64 + j * 16 + la15;
        const float v = acc[i][j][q];
        const float h = (MODE == 0) ? (sc * v * (1.f / (1.f + __expf(-v)))) : v;
        outBF[(size_t)(off + m0 + rloc) * OS + col] = f2bf(h);
      }
    }
  }
}

// ---------------- gather-sum: out[n] = alpha*(Yc[p1]+Yc[p2]+Yc[8192+n]) + beta*x[n] --------
__global__ __launch_bounds__(256) void gather_kernel(
    const u16* __restrict__ Yc, const int* __restrict__ pos,
    const float* __restrict__ x, const float* __restrict__ alpha,
    const float* __restrict__ beta, float* __restrict__ out)
{
  const int n = blockIdx.x;
  const int c0 = threadIdx.x * 8;
  const int p1 = pos[2 * n], p2 = pos[2 * n + 1];
  const bf16x8 a = *(const bf16x8*)(Yc + (size_t)p1 * CD + c0);
  const bf16x8 b = *(const bf16x8*)(Yc + (size_t)p2 * CD + c0);
  const bf16x8 s = *(const bf16x8*)(Yc + ((size_t)RROWS + n) * CD + c0);
  const float* xr = x + (size_t)n * CD + c0;
  float* orow = out + (size_t)n * CD + c0;
#pragma unroll
  for (int j = 0; j < 8; ++j) {
    const float v = (float)a[j] + (float)b[j] + (float)s[j];
    orow[j] = alpha[c0 + j] * v + beta[c0 + j] * xr[j];
  }
}

extern "C" void kernel_launch(void* const* d_in, const int* in_sizes, int n_in,
                              void* d_out, int out_size, void* d_ws, size_t ws_size,
                              hipStream_t stream)
{
  (void)in_sizes; (void)n_in; (void)out_size; (void)ws_size;
  const float* x     = (const float*)d_in[0];
  const float* gw    = (const float*)d_in[1];
  const float* w1    = (const float*)d_in[2];
  const float* w2    = (const float*)d_in[3];
  const float* sw1   = (const float*)d_in[4];
  const float* sw2   = (const float*)d_in[5];
  const float* alpha = (const float*)d_in[6];
  const float* beta  = (const float*)d_in[7];
  float* out = (float*)d_out;

  char* ws = (char*)d_ws;
  float* combine = (float*)(ws + 0);            // 256 KB
  float* part    = (float*)(ws + 262144);       // 64 KB
  int*   sel     = (int*)(ws + 327680);         // 16 KB
  int*   le      = (int*)(ws + 344064);         // 32 KB
  int*   pos     = (int*)(ws + 376832);         // 32 KB
  int*   cntoff  = (int*)(ws + 409600);         // 256 B
  int*   tileMap = (int*)(ws + 409856);         // 512 B
  u16*   xb      = (u16*)(ws + 410368);         // 16 MB
  u16*   w1b     = (u16*)(ws + 17187584);       // 51.9 MB (w1 x8, then sw1)
  u16*   w2b     = (u16*)(ws + 69092096);       // 51.9 MB (w2 x8, then sw2)
  u16*   Hcomp   = (u16*)(ws + 120996608);      // 12288*1408*2 = 34.6 MB
  u16*   Ycomp   = (u16*)(ws + 155599616);      // 12288*2048*2 = 50.3 MB

  gate_kernel<<<1024, 256, 0, stream>>>(x, gw, combine, part, sel, xb);
  route_kernel<<<1, 64, 0, stream>>>(sel, le, pos, cntoff, tileMap);
  finalize_kernel<<<1, 256, 0, stream>>>(part, out + (size_t)TOKS * CD);
  cast_all_kernel<<<4096, 256, 0, stream>>>((const float4*)w1, (const float4*)sw1,
                                            (const float4*)w2, (const float4*)sw2, w1b, w2b);
  gemm_bt<0><<<dim3(NTMAX, 11), 256, 0, stream>>>(xb, w1b, Hcomp, combine, le, cntoff, tileMap);
  gemm_bt<1><<<dim3(NTMAX, 16), 256, 0, stream>>>(Hcomp, w2b, Ycomp, nullptr, nullptr, cntoff, tileMap);
  gather_kernel<<<TOKS, 256, 0, stream>>>(Ycomp, pos, x, alpha, beta, out);
}